// Round 2
// 1841.760 us; speedup vs baseline: 1.1015x; 1.1015x over previous
//
#include <hip/hip_runtime.h>

// CrossBatchEmbeddingMixer: B=8192, H=4096, GH=1024, TEMP=1
// bf16 MFMA GEMMs, fp32 accumulate, fused epilogues.
// Big GEMMs (proj/sim/valuesT/cross/final) on a 256x256 8-wave pipelined
// kernel (BK=32, 4-slot LDS ring, counted vmcnt(8) - never drained to 0 in
// the main loop, st_16x32 LDS XOR swizzle fed by pre-swizzled global_load_lds
// sources, setprio around MFMA clusters, bijective XCD block swizzle).
// h1 GEMMs (N=1024) stay on the 128^2 kernel (grid fit: 512 vs 128 blocks).

#define HDIM 4096
#define BATCH 8192
#define GHDIM 1024

typedef unsigned short u16;
typedef short bf16x8 __attribute__((ext_vector_type(8)));
typedef float f32x4 __attribute__((ext_vector_type(4)));

__device__ __forceinline__ u16 f2bf(float f) {
  union { float f; unsigned u; } v; v.f = f;
  unsigned r = v.u + 0x7FFFu + ((v.u >> 16) & 1u);
  return (u16)(r >> 16);
}
__device__ __forceinline__ float bf2f(u16 u) {
  union { unsigned u; float f; } v; v.u = ((unsigned)u) << 16;
  return v.f;
}

// ---------------- cast fp32 -> bf16 (vectorized) ----------------
__global__ void cast_f32_bf16(const float* __restrict__ src, u16* __restrict__ dst, int n4) {
  int i = blockIdx.x * 256 + threadIdx.x;
  if (i < n4) {
    float4 f = ((const float4*)src)[i];
    ushort4 o;
    o.x = f2bf(f.x); o.y = f2bf(f.y); o.z = f2bf(f.z); o.w = f2bf(f.w);
    ((ushort4*)dst)[i] = o;
  }
}

// ---------------- mask canonicalization ----------------
__global__ void detect_mask(const unsigned char* __restrict__ m, int nbytes, int* __restrict__ flag) {
  __shared__ int cnt[256];
  int c = 0;
  for (int i = threadIdx.x; i < nbytes; i += 256)
    if ((i & 3) && m[i]) c++;
  cnt[threadIdx.x] = c;
  __syncthreads();
  for (int s = 128; s > 0; s >>= 1) {
    if ((int)threadIdx.x < s) cnt[threadIdx.x] += cnt[threadIdx.x + s];
    __syncthreads();
  }
  if (threadIdx.x == 0) *flag = cnt[0];
}

// ---------------- compact valid column indices ----------------
// kinfo[0]=kc, kinfo[1]=kc rounded up to 256 (256-tile-aligned for gemm256).
__global__ void compact_mask(const void* __restrict__ raw, const int* __restrict__ flag,
                             int* __restrict__ idxc, int* __restrict__ kinfo) {
  const int t = threadIdx.x;
  const bool isbool = (*flag > 0);
  __shared__ int cnt[256];
  __shared__ int total;
  const int base0 = t * 32;
  int c = 0;
  for (int i = 0; i < 32; i++) {
    int gi = base0 + i;
    int v = isbool ? ((const unsigned char*)raw)[gi] : ((const int*)raw)[gi];
    if (v) c++;
  }
  cnt[t] = c;
  __syncthreads();
  if (t == 0) {
    int acc = 0;
    for (int i = 0; i < 256; i++) { int x = cnt[i]; cnt[i] = acc; acc += x; }
    total = acc;
    kinfo[0] = acc;
    kinfo[1] = (acc + 255) & ~255;
  }
  __syncthreads();
  int w = cnt[t];
  for (int i = 0; i < 32; i++) {
    int gi = base0 + i;
    int v = isbool ? ((const unsigned char*)raw)[gi] : ((const int*)raw)[gi];
    if (v) idxc[w++] = gi;
  }
  for (int i = total + t; i < BATCH; i += 256) idxc[i] = -1;
}

// ---------------- gather valid rows [kc_pad, H], zero-fill pad rows ----------------
__global__ void gather_rows(const u16* __restrict__ src, u16* __restrict__ dst,
                            const int* __restrict__ idxc, const int* __restrict__ kinfo) {
  int c = blockIdx.x;
  int kc = kinfo[0], kp = kinfo[1];
  if (c >= kp) return;
  uint4* d = (uint4*)(dst + (size_t)c * HDIM);
  if (c < kc) {
    const uint4* s = (const uint4*)(src + (size_t)idxc[c] * HDIM);
    d[threadIdx.x] = s[threadIdx.x];
    d[threadIdx.x + 256] = s[threadIdx.x + 256];
  } else {
    uint4 z = {0, 0, 0, 0};
    d[threadIdx.x] = z;
    d[threadIdx.x + 256] = z;
  }
}

// ---------------- row L2-normalize (in place, bf16 [BATCH][HDIM]) ----------------
__global__ void normalize_rows(u16* __restrict__ p) {
  int row = blockIdx.x;
  uint4* r = (uint4*)(p + (size_t)row * HDIM);
  uint4 d[2];
  float s = 0.f;
#pragma unroll
  for (int i = 0; i < 2; i++) {
    d[i] = r[i * 256 + threadIdx.x];
    const u16* u = (const u16*)&d[i];
#pragma unroll
    for (int j = 0; j < 8; j++) { float f = bf2f(u[j]); s += f * f; }
  }
  __shared__ float red[256];
  red[threadIdx.x] = s;
  __syncthreads();
  for (int st = 128; st > 0; st >>= 1) {
    if ((int)threadIdx.x < st) red[threadIdx.x] += red[threadIdx.x + st];
    __syncthreads();
  }
  float scale = 1.0f / fmaxf(sqrtf(red[0]), 1e-12f);
#pragma unroll
  for (int i = 0; i < 2; i++) {
    u16* u = (u16*)&d[i];
#pragma unroll
    for (int j = 0; j < 8; j++) u[j] = f2bf(bf2f(u[j]) * scale);
    r[i * 256 + threadIdx.x] = d[i];
  }
}

// ---------------- row softmax over kc_pad compacted cols (in place, ld=BATCH) ----------------
__global__ void softmax_rows_dyn(u16* __restrict__ sim, const int* __restrict__ kinfo) {
  const int kp = kinfo[1];
  const int row = blockIdx.x;
  uint4* r = (uint4*)(sim + (size_t)row * BATCH);
  float v[32];
  int active[4];
  float mx = -3.0e38f;
#pragma unroll
  for (int ch = 0; ch < 4; ch++) {
    int base = ch * 2048 + threadIdx.x * 8;
    active[ch] = (base < kp);
    if (active[ch]) {
      uint4 d = r[ch * 256 + threadIdx.x];
      const u16* u = (const u16*)&d;
#pragma unroll
      for (int j = 0; j < 8; j++) {
        float f = bf2f(u[j]);
        v[ch * 8 + j] = f;
        mx = fmaxf(mx, f);
      }
    }
  }
  __shared__ float red[256];
  red[threadIdx.x] = mx;
  __syncthreads();
  for (int st = 128; st > 0; st >>= 1) {
    if ((int)threadIdx.x < st) red[threadIdx.x] = fmaxf(red[threadIdx.x], red[threadIdx.x + st]);
    __syncthreads();
  }
  mx = red[0];
  __syncthreads();
  float s = 0.f;
#pragma unroll
  for (int ch = 0; ch < 4; ch++) {
    if (active[ch]) {
#pragma unroll
      for (int j = 0; j < 8; j++) {
        float e = (v[ch * 8 + j] < -1.0e30f) ? 0.f : __expf(v[ch * 8 + j] - mx);
        v[ch * 8 + j] = e;
        s += e;
      }
    }
  }
  red[threadIdx.x] = s;
  __syncthreads();
  for (int st = 128; st > 0; st >>= 1) {
    if ((int)threadIdx.x < st) red[threadIdx.x] += red[threadIdx.x + st];
    __syncthreads();
  }
  float inv = (red[0] > 0.f) ? 1.0f / red[0] : 0.f;
#pragma unroll
  for (int ch = 0; ch < 4; ch++) {
    if (active[ch]) {
      uint4 d;
      u16* u = (u16*)&d;
#pragma unroll
      for (int j = 0; j < 8; j++) u[j] = f2bf(v[ch * 8 + j] * inv);
      r[ch * 256 + threadIdx.x] = d;
    }
  }
}

enum { EPI_BF16 = 0, EPI_SIM = 1, EPI_F32 = 2, EPI_GELU = 3, EPI_FINAL = 4 };

__device__ __forceinline__ void async_load16(const u16* g, u16* l) {
  __builtin_amdgcn_global_load_lds(
      (const __attribute__((address_space(1))) void*)g,
      (__attribute__((address_space(3))) void*)l, 16, 0, 0);
}

// ============================================================================
// gemm256: C[M][N] = A[M][K] @ B[N][K]^T, 256x256 tile, BK=32, 512 thr (8 waves
// 2Mx4N), per-wave 128x64 via 8x4 mfma_f32_16x16x32_bf16.
//
// Pipeline invariants (audited r1 — race-free):
//  - LDS ring: 4 slots x (A 16KB + B 16KB) = 128 KB. Tile t lives in slot t&3.
//  - Block t: 2 phases, each = {ds_read frags, 2x global_load_lds for tile t+3,
//    s_barrier, setprio(1), 16 MFMA, setprio(0), s_barrier}.
//  - Block-end (BEFORE final barrier): s_waitcnt vmcnt(8). vmcnt is per-wave,
//    but every wave executes its own vmcnt(8) before the barrier, so after the
//    barrier ALL waves' loads older than the newest 8 (tiles t+2,t+3) have
//    landed => tile t+1 fully resident. vmcnt never drains to 0 in-loop;
//    issue->consume distance = 3 blocks (~6 phases) >> HBM latency.
//  - Slot reuse: stages for tile t+3 (slot (t-1)&3) are issued in block t,
//    strictly after the barrier ending block t-1; all waves' ds_reads of tile
//    t-1 completed before their MFMAs (compiler lgkmcnt) hence before that
//    barrier.
//  - LDS image: st_16x32 swizzle. Element (row,col) of a 256x32 bf16 tile at
//    byte swz(lin), lin = row*64 + col*2, swz(x) = x ^ (((x>>9)&1)<<5).
//    global_load_lds writes linearly (wave-uniform base + lane*16), so the
//    global source per thread is pre-swizzled (both-sides-or-neither):
//    thread writes tile byte x = i*8192 + tid*16  <=>  global element
//    (row = i*128 + wave*16 + (lane>>2), col = ((lane&3)<<3)^(((lane>>5)&1)<<4)).
//    Read XOR cancels (involution).
//  - Accumulation k-order identical to the 128^2 kernel (numerics unchanged).
// ============================================================================
template <int EPI>
__global__ __launch_bounds__(512, 2) void gemm256(
    const u16* __restrict__ A, int lda,
    const u16* __restrict__ B, int ldb,
    void* __restrict__ C, int ldc,
    int M, int N, int K,
    const int* __restrict__ kinfo, int dynN, int dynK,
    const int* __restrict__ idxc,
    const float* __restrict__ aux,
    const u16* __restrict__ aux2,
    const float* __restrict__ bias) {
  // bijective XCD-aware block swizzle (T1, m204 formula)
  const int nwg = (int)(gridDim.x * gridDim.y);
  const int orig = (int)(blockIdx.y * gridDim.x + blockIdx.x);
  int wgid;
  {
    int q = nwg >> 3, r = nwg & 7, x = orig & 7, lo = orig >> 3;
    wgid = (x < r ? x * (q + 1) : r * (q + 1) + (x - r) * q) + lo;
  }
  const int bx = wgid % (int)gridDim.x;
  const int by = wgid / (int)gridDim.x;
  const int rowBase = by * 256;
  const int colBase = bx * 256;
  if (dynN && colBase >= kinfo[1]) return;  // block-uniform, precedes all barriers
  const int Keff = dynK ? kinfo[1] : K;
  const int NT = Keff >> 5;  // K-tiles of 32

  __shared__ __align__(16) u16 sm[4 * 16384];  // 4 slots x (A 8192 + B 8192) u16

  const int tid = threadIdx.x;
  const int lane = tid & 63, wave = tid >> 6;
  const int wm = wave >> 2, wn = wave & 3;   // 2M x 4N
  const int fr = lane & 15, kq = lane >> 4;  // frag row / k-chunk

  // frag LDS byte offsets (constant across tiles); bit9 of lin = fr bit 3
  int aOff[8], bOff[4];
#pragma unroll
  for (int mi = 0; mi < 8; mi++) {
    int lin = ((wm * 8 + mi) << 10) + (fr << 6) + (kq << 4);
    aOff[mi] = lin ^ (((fr >> 3) & 1) << 5);
  }
#pragma unroll
  for (int ni = 0; ni < 4; ni++) {
    int lin = ((wn * 4 + ni) << 10) + (fr << 6) + (kq << 4);
    bOff[ni] = (lin ^ (((fr >> 3) & 1) << 5)) + 16384;  // B half of slot (+16KB)
  }

  // staging coords (pre-swizzled global source, linear LDS dest)
  const int i0row = wave * 16 + (lane >> 2);                        // + i*128
  const int scol = ((lane & 3) << 3) ^ (((lane >> 5) & 1) << 4);    // 8-aligned

  auto stageA = [&](int tt) {
    const int sb = (tt & 3) * 16384;
    const int kt = tt << 5;
#pragma unroll
    for (int i = 0; i < 2; i++)
      async_load16(A + (size_t)(rowBase + i * 128 + i0row) * lda + kt + scol,
                   sm + sb + i * 4096 + tid * 8);
  };
  auto stageB = [&](int tt) {
    const int sb = (tt & 3) * 16384 + 8192;
    const int kt = tt << 5;
#pragma unroll
    for (int i = 0; i < 2; i++)
      async_load16(B + (size_t)(colBase + i * 128 + i0row) * ldb + kt + scol,
                   sm + sb + i * 4096 + tid * 8);
  };

  f32x4 zero = {0.f, 0.f, 0.f, 0.f};
  f32x4 acc[8][4];
#pragma unroll
  for (int mi = 0; mi < 8; mi++)
#pragma unroll
    for (int ni = 0; ni < 4; ni++) acc[mi][ni] = zero;

  // prologue: stage tiles 0..2 (12 loads); vmcnt(8) -> oldest 4 done = tile 0
  if (NT > 0) { stageA(0); stageB(0); }
  if (NT > 1) { stageA(1); stageB(1); }
  if (NT > 2) { stageA(2); stageB(2); }
  if (NT >= 3)      asm volatile("s_waitcnt vmcnt(8)" ::: "memory");
  else if (NT == 2) asm volatile("s_waitcnt vmcnt(4)" ::: "memory");
  else              asm volatile("s_waitcnt vmcnt(0)" ::: "memory");
  __builtin_amdgcn_sched_barrier(0);
  __builtin_amdgcn_s_barrier();

  for (int t = 0; t < NT; ++t) {
    const char* slot = (const char*)sm + (size_t)(t & 3) * 32768;
    const int pt = t + 3;
    const bool pf = pt < NT;

    bf16x8 af[4], bf[4];
    // ---- phase 0: frags (A mi 0-3, B all), stage A(t+3), 16 MFMA ----
#pragma unroll
    for (int mi = 0; mi < 4; mi++) af[mi] = *(const bf16x8*)(slot + aOff[mi]);
#pragma unroll
    for (int ni = 0; ni < 4; ni++) bf[ni] = *(const bf16x8*)(slot + bOff[ni]);
    if (pf) stageA(pt);
    __builtin_amdgcn_s_barrier();
    __builtin_amdgcn_s_setprio(1);
#pragma unroll
    for (int mi = 0; mi < 4; mi++)
#pragma unroll
      for (int ni = 0; ni < 4; ni++)
        acc[mi][ni] = __builtin_amdgcn_mfma_f32_16x16x32_bf16(af[mi], bf[ni], acc[mi][ni], 0, 0, 0);
    __builtin_amdgcn_s_setprio(0);
    __builtin_amdgcn_s_barrier();

    // ---- phase 1: frags (A mi 4-7; B cached in regs), stage B(t+3), 16 MFMA ----
#pragma unroll
    for (int mi = 0; mi < 4; mi++) af[mi] = *(const bf16x8*)(slot + aOff[mi + 4]);
    if (pf) stageB(pt);
    __builtin_amdgcn_s_barrier();
    __builtin_amdgcn_s_setprio(1);
#pragma unroll
    for (int mi = 0; mi < 4; mi++)
#pragma unroll
      for (int ni = 0; ni < 4; ni++)
        acc[mi + 4][ni] = __builtin_amdgcn_mfma_f32_16x16x32_bf16(af[mi], bf[ni], acc[mi + 4][ni], 0, 0, 0);
    __builtin_amdgcn_s_setprio(0);
    // counted drain: keep tiles {t+2, t+3} in flight; tile t+1 now resident
    if (pf)                asm volatile("s_waitcnt vmcnt(8)" ::: "memory");
    else if (t + 2 < NT)   asm volatile("s_waitcnt vmcnt(4)" ::: "memory");
    else if (t + 1 < NT)   asm volatile("s_waitcnt vmcnt(0)" ::: "memory");
    __builtin_amdgcn_sched_barrier(0);
    __builtin_amdgcn_s_barrier();
  }

  // Epilogue. C/D layout: col = lane&15, row = (lane>>4)*4 + reg  [m89-verified]
  const int quad = lane >> 4, lcol = lane & 15;
#pragma unroll
  for (int mi = 0; mi < 8; mi++) {
#pragma unroll
    for (int ni = 0; ni < 4; ni++) {
#pragma unroll
      for (int r = 0; r < 4; r++) {
        int grow = rowBase + wm * 128 + mi * 16 + quad * 4 + r;
        int gcol = colBase + wn * 64 + ni * 16 + lcol;
        float v = acc[mi][ni][r];
        size_t idx = (size_t)grow * ldc + gcol;
        if constexpr (EPI == EPI_BF16) {
          ((u16*)C)[idx] = f2bf(v);
        } else if constexpr (EPI == EPI_SIM) {
          bool dead = (gcol >= kinfo[0]) || (idxc[gcol] == grow);
          ((u16*)C)[idx] = dead ? (u16)0xFF80 : f2bf(v);
        } else if constexpr (EPI == EPI_F32) {
          ((float*)C)[idx] = v;
        } else if constexpr (EPI == EPI_GELU) {
          float x = v + aux[idx] + bias[gcol];
          float g = 0.5f * x * (1.0f + erff(x * 0.70710678118654752f));
          ((u16*)C)[idx] = f2bf(g);
        } else {  // EPI_FINAL
          float x = v + bias[gcol];
          float g = 1.0f / (1.0f + __expf(-x));
          ((float*)C)[idx] = aux[idx] + g * bf2f(aux2[idx]);
        }
      }
    }
  }
}

// ---------------- 128x128 m97-structure GEMM (kept for the N=1024 h1 passes) ----------------
template <int EPI>
__global__ __launch_bounds__(256) void gemm_bt(
    const u16* __restrict__ A, int lda,
    const u16* __restrict__ B, int ldb,
    void* __restrict__ C, int ldc,
    int M, int N, int K,
    const int* __restrict__ kinfo, int dynN, int dynK,
    const int* __restrict__ idxc,
    const float* __restrict__ aux,
    const u16* __restrict__ aux2,
    const float* __restrict__ bias) {
  const int rowBase = blockIdx.y * 128;
  const int colBase = blockIdx.x * 128;
  if (dynN && colBase >= kinfo[1]) return;
  const int Keff = dynK ? kinfo[1] : K;

  __shared__ __align__(16) u16 lA[128 * 64];
  __shared__ __align__(16) u16 lB[128 * 64];
  const int tid = threadIdx.x;
  const int lane = tid & 63;
  const int wave = tid >> 6;
  const int waveRow = (wave >> 1) * 64;
  const int waveCol = (wave & 1) * 64;

  const u16* Ab = A + (size_t)rowBase * lda;
  const u16* Bb = B + (size_t)colBase * ldb;

  f32x4 zero = {0.f, 0.f, 0.f, 0.f};
  f32x4 acc[4][4];
#pragma unroll
  for (int mi = 0; mi < 4; mi++)
#pragma unroll
    for (int ni = 0; ni < 4; ni++) acc[mi][ni] = zero;

  for (int kt = 0; kt < Keff; kt += 64) {
#pragma unroll
    for (int i = 0; i < 4; i++) {
      int c = i * 256 + tid;
      int row = c >> 3, k8 = c & 7;
      int gk8 = k8 ^ (row & 7);
      async_load16(Ab + (size_t)row * lda + kt + gk8 * 8, &lA[c * 8]);
    }
#pragma unroll
    for (int i = 0; i < 4; i++) {
      int c = i * 256 + tid;
      int row = c >> 3, k8 = c & 7;
      int gk8 = k8 ^ (row & 7);
      async_load16(Bb + (size_t)row * ldb + kt + gk8 * 8, &lB[c * 8]);
    }
    __syncthreads();
#pragma unroll
    for (int ks = 0; ks < 2; ks++) {
      const int kq = ks * 4 + (lane >> 4);
      bf16x8 af[4], bfr[4];
#pragma unroll
      for (int mi = 0; mi < 4; mi++) {
        int row = waveRow + mi * 16 + (lane & 15);
        af[mi] = *(const bf16x8*)&lA[row * 64 + ((kq ^ (row & 7)) * 8)];
      }
#pragma unroll
      for (int ni = 0; ni < 4; ni++) {
        int row = waveCol + ni * 16 + (lane & 15);
        bfr[ni] = *(const bf16x8*)&lB[row * 64 + ((kq ^ (row & 7)) * 8)];
      }
#pragma unroll
      for (int mi = 0; mi < 4; mi++)
#pragma unroll
        for (int ni = 0; ni < 4; ni++)
          acc[mi][ni] = __builtin_amdgcn_mfma_f32_16x16x32_bf16(af[mi], bfr[ni], acc[mi][ni], 0, 0, 0);
    }
    __syncthreads();
  }

  const int quad = lane >> 4, lcol = lane & 15;
#pragma unroll
  for (int mi = 0; mi < 4; mi++) {
#pragma unroll
    for (int ni = 0; ni < 4; ni++) {
#pragma unroll
      for (int r = 0; r < 4; r++) {
        int grow = rowBase + waveRow + mi * 16 + quad * 4 + r;
        int gcol = colBase + waveCol + ni * 16 + lcol;
        float v = acc[mi][ni][r];
        size_t idx = (size_t)grow * ldc + gcol;
        if constexpr (EPI == EPI_BF16) {
          ((u16*)C)[idx] = f2bf(v);
        } else if constexpr (EPI == EPI_SIM) {
          bool dead = (gcol >= kinfo[0]) || (idxc[gcol] == grow);
          ((u16*)C)[idx] = dead ? (u16)0xFF80 : f2bf(v);
        } else if constexpr (EPI == EPI_F32) {
          ((float*)C)[idx] = v;
        } else if constexpr (EPI == EPI_GELU) {
          float x = v + aux[idx] + bias[gcol];
          float g = 0.5f * x * (1.0f + erff(x * 0.70710678118654752f));
          ((u16*)C)[idx] = f2bf(g);
        } else {
          float x = v + bias[gcol];
          float g = 1.0f / (1.0f + __expf(-x));
          ((float*)C)[idx] = aux[idx] + g * bf2f(aux2[idx]);
        }
      }
    }
  }
}

// ---------------- host launch ----------------
extern "C" void kernel_launch(void* const* d_in, const int* in_sizes, int n_in,
                              void* d_out, int out_size, void* d_ws, size_t ws_size,
                              hipStream_t stream) {
  const float* hs   = (const float*)d_in[0];
  const void*  mraw = d_in[1];
  const float* Wsim = (const float*)d_in[2];
  const float* Wval = (const float*)d_in[3];
  const float* Wg1  = (const float*)d_in[4];
  const float* bg1  = (const float*)d_in[5];
  const float* Wg2  = (const float*)d_in[6];
  const float* bg2  = (const float*)d_in[7];
  float* out = (float*)d_out;

  char* ws = (char*)d_ws;
  size_t off = 0;
  auto alloc = [&](size_t bytes) {
    char* p = ws + off;
    off += (bytes + 255) & ~(size_t)255;
    return p;
  };
  u16* hidden_bf = (u16*)alloc((size_t)BATCH * HDIM * 2);
  u16* wbuf      = (u16*)alloc((size_t)HDIM * HDIM * 2);
  u16* r1        = (u16*)alloc((size_t)BATCH * HDIM * 2);
  u16* r2        = (u16*)alloc((size_t)BATCH * HDIM * 2);
  int* idxc      = (int*)alloc((size_t)BATCH * 4);
  int* kinfo     = (int*)alloc(256);
  int* flag      = (int*)alloc(256);
  if (off > ws_size) return;

  u16*   simw  = (u16*)d_out;
  float* h1acc = (float*)d_out;
  (void)in_sizes; (void)n_in; (void)out_size;

  dim3 blk(256);
  dim3 blk5(512);

  detect_mask<<<1, 256, 0, stream>>>((const unsigned char*)mraw, BATCH, flag);
  compact_mask<<<1, 256, 0, stream>>>(mraw, flag, idxc, kinfo);

  cast_f32_bf16<<<(BATCH * HDIM / 4) / 256, 256, 0, stream>>>(hs, hidden_bf, BATCH * HDIM / 4);

  // proj = hidden @ Wsim^T  [B, H] -> r1
  cast_f32_bf16<<<(HDIM * HDIM / 4) / 256, 256, 0, stream>>>(Wsim, wbuf, HDIM * HDIM / 4);
  gemm256<EPI_BF16><<<dim3(HDIM / 256, BATCH / 256), blk5, 0, stream>>>(
      hidden_bf, HDIM, wbuf, HDIM, r1, HDIM, BATCH, HDIM, HDIM,
      nullptr, 0, 0, nullptr, nullptr, nullptr, nullptr);
  normalize_rows<<<BATCH, 256, 0, stream>>>(r1);

  gather_rows<<<BATCH, 256, 0, stream>>>(r1, r2, idxc, kinfo);

  // sim = normed @ normed_c^T  [B, kc_pad] (ld=BATCH) -> simw
  gemm256<EPI_SIM><<<dim3(BATCH / 256, BATCH / 256), blk5, 0, stream>>>(
      r1, HDIM, r2, HDIM, simw, BATCH, BATCH, BATCH, HDIM,
      kinfo, 1, 0, idxc, nullptr, nullptr, nullptr);
  softmax_rows_dyn<<<BATCH, 256, 0, stream>>>(simw, kinfo);

  gather_rows<<<BATCH, 256, 0, stream>>>(hidden_bf, r1, idxc, kinfo);

  // valuesT_c = Wval @ hidden_c^T  [H, kc_pad] (ld=BATCH) -> r2
  cast_f32_bf16<<<(HDIM * HDIM / 4) / 256, 256, 0, stream>>>(Wval, wbuf, HDIM * HDIM / 4);
  gemm256<EPI_BF16><<<dim3(BATCH / 256, HDIM / 256), blk5, 0, stream>>>(
      wbuf, HDIM, r1, HDIM, r2, BATCH, HDIM, BATCH, HDIM,
      kinfo, 1, 0, nullptr, nullptr, nullptr, nullptr);

  // cross = weights_c @ valuesT_c^T  [B, H], K = kc_pad -> r1
  gemm256<EPI_BF16><<<dim3(HDIM / 256, BATCH / 256), blk5, 0, stream>>>(
      simw, BATCH, r2, BATCH, r1, HDIM, BATCH, HDIM, BATCH,
      kinfo, 0, 1, nullptr, nullptr, nullptr, nullptr);

  // h1 pass 1: hidden @ Wg1[:, :H]^T -> fp32 acc (d_out)  [B, GH]
  cast_f32_bf16<<<(GHDIM * 2 * HDIM / 4) / 256, 256, 0, stream>>>(Wg1, wbuf, GHDIM * 2 * HDIM / 4);
  gemm_bt<EPI_F32><<<dim3(GHDIM / 128, BATCH / 128), blk, 0, stream>>>(
      hidden_bf, HDIM, wbuf, 2 * HDIM, h1acc, GHDIM, BATCH, GHDIM, HDIM,
      nullptr, 0, 0, nullptr, nullptr, nullptr, nullptr);
  // h1 pass 2: + cross @ Wg1[:, H:]^T, + b_g1, exact GELU -> r2
  gemm_bt<EPI_GELU><<<dim3(GHDIM / 128, BATCH / 128), blk, 0, stream>>>(
      r1, HDIM, wbuf + HDIM, 2 * HDIM, r2, GHDIM, BATCH, GHDIM, HDIM,
      nullptr, 0, 0, nullptr, h1acc, nullptr, bg1);

  // out = hidden + sigmoid(h1 @ Wg2^T + b_g2) * cross  [B, H] fp32 -> d_out
  cast_f32_bf16<<<(HDIM * GHDIM / 4) / 256, 256, 0, stream>>>(Wg2, wbuf, HDIM * GHDIM / 4);
  gemm256<EPI_FINAL><<<dim3(HDIM / 256, BATCH / 256), blk5, 0, stream>>>(
      r2, GHDIM, wbuf, GHDIM, out, HDIM, BATCH, HDIM, GHDIM,
      nullptr, 0, 0, nullptr, hs, r1, bg2);
}

// Round 3
// 1807.646 us; speedup vs baseline: 1.1223x; 1.0189x over previous
//
#include <hip/hip_runtime.h>

// CrossBatchEmbeddingMixer: B=8192, H=4096, GH=1024, TEMP=1
// bf16 MFMA GEMMs, fp32 accumulate, fused epilogues.
// gemm256 v2: 256x256 tile, BK=32, 4-slot LDS ring, counted vmcnt AND counted
// lgkmcnt with one-phase-ahead fragment pre-read (register ping-pong), so the
// LDS->reg traffic of phase i+1 drains under the MFMA cluster of phase i.
// One barrier per phase (2 per K-tile). st_16x32 swizzle, setprio, XCD swizzle.
// h1 GEMMs (N=1024) stay on the 128^2 kernel (grid fit: 512 vs 128 blocks).

#define HDIM 4096
#define BATCH 8192
#define GHDIM 1024

typedef unsigned short u16;
typedef short bf16x8 __attribute__((ext_vector_type(8)));
typedef float f32x4 __attribute__((ext_vector_type(4)));

__device__ __forceinline__ u16 f2bf(float f) {
  union { float f; unsigned u; } v; v.f = f;
  unsigned r = v.u + 0x7FFFu + ((v.u >> 16) & 1u);
  return (u16)(r >> 16);
}
__device__ __forceinline__ float bf2f(u16 u) {
  union { unsigned u; float f; } v; v.u = ((unsigned)u) << 16;
  return v.f;
}

// ---------------- cast fp32 -> bf16 (vectorized) ----------------
__global__ void cast_f32_bf16(const float* __restrict__ src, u16* __restrict__ dst, int n4) {
  int i = blockIdx.x * 256 + threadIdx.x;
  if (i < n4) {
    float4 f = ((const float4*)src)[i];
    ushort4 o;
    o.x = f2bf(f.x); o.y = f2bf(f.y); o.z = f2bf(f.z); o.w = f2bf(f.w);
    ((ushort4*)dst)[i] = o;
  }
}

// ---------------- mask canonicalization ----------------
__global__ void detect_mask(const unsigned char* __restrict__ m, int nbytes, int* __restrict__ flag) {
  __shared__ int cnt[256];
  int c = 0;
  for (int i = threadIdx.x; i < nbytes; i += 256)
    if ((i & 3) && m[i]) c++;
  cnt[threadIdx.x] = c;
  __syncthreads();
  for (int s = 128; s > 0; s >>= 1) {
    if ((int)threadIdx.x < s) cnt[threadIdx.x] += cnt[threadIdx.x + s];
    __syncthreads();
  }
  if (threadIdx.x == 0) *flag = cnt[0];
}

// ---------------- compact valid column indices ----------------
// kinfo[0]=kc, kinfo[1]=kc rounded up to 256 (256-tile-aligned for gemm256).
__global__ void compact_mask(const void* __restrict__ raw, const int* __restrict__ flag,
                             int* __restrict__ idxc, int* __restrict__ kinfo) {
  const int t = threadIdx.x;
  const bool isbool = (*flag > 0);
  __shared__ int cnt[256];
  __shared__ int total;
  const int base0 = t * 32;
  int c = 0;
  for (int i = 0; i < 32; i++) {
    int gi = base0 + i;
    int v = isbool ? ((const unsigned char*)raw)[gi] : ((const int*)raw)[gi];
    if (v) c++;
  }
  cnt[t] = c;
  __syncthreads();
  if (t == 0) {
    int acc = 0;
    for (int i = 0; i < 256; i++) { int x = cnt[i]; cnt[i] = acc; acc += x; }
    total = acc;
    kinfo[0] = acc;
    kinfo[1] = (acc + 255) & ~255;
  }
  __syncthreads();
  int w = cnt[t];
  for (int i = 0; i < 32; i++) {
    int gi = base0 + i;
    int v = isbool ? ((const unsigned char*)raw)[gi] : ((const int*)raw)[gi];
    if (v) idxc[w++] = gi;
  }
  for (int i = total + t; i < BATCH; i += 256) idxc[i] = -1;
}

// ---------------- gather valid rows [kc_pad, H], zero-fill pad rows ----------------
__global__ void gather_rows(const u16* __restrict__ src, u16* __restrict__ dst,
                            const int* __restrict__ idxc, const int* __restrict__ kinfo) {
  int c = blockIdx.x;
  int kc = kinfo[0], kp = kinfo[1];
  if (c >= kp) return;
  uint4* d = (uint4*)(dst + (size_t)c * HDIM);
  if (c < kc) {
    const uint4* s = (const uint4*)(src + (size_t)idxc[c] * HDIM);
    d[threadIdx.x] = s[threadIdx.x];
    d[threadIdx.x + 256] = s[threadIdx.x + 256];
  } else {
    uint4 z = {0, 0, 0, 0};
    d[threadIdx.x] = z;
    d[threadIdx.x + 256] = z;
  }
}

// ---------------- row L2-normalize (in place, bf16 [BATCH][HDIM]) ----------------
__global__ void normalize_rows(u16* __restrict__ p) {
  int row = blockIdx.x;
  uint4* r = (uint4*)(p + (size_t)row * HDIM);
  uint4 d[2];
  float s = 0.f;
#pragma unroll
  for (int i = 0; i < 2; i++) {
    d[i] = r[i * 256 + threadIdx.x];
    const u16* u = (const u16*)&d[i];
#pragma unroll
    for (int j = 0; j < 8; j++) { float f = bf2f(u[j]); s += f * f; }
  }
  __shared__ float red[256];
  red[threadIdx.x] = s;
  __syncthreads();
  for (int st = 128; st > 0; st >>= 1) {
    if ((int)threadIdx.x < st) red[threadIdx.x] += red[threadIdx.x + st];
    __syncthreads();
  }
  float scale = 1.0f / fmaxf(sqrtf(red[0]), 1e-12f);
#pragma unroll
  for (int i = 0; i < 2; i++) {
    u16* u = (u16*)&d[i];
#pragma unroll
    for (int j = 0; j < 8; j++) u[j] = f2bf(bf2f(u[j]) * scale);
    r[i * 256 + threadIdx.x] = d[i];
  }
}

// ---------------- row softmax over kc_pad compacted cols (in place, ld=BATCH) ----------------
__global__ void softmax_rows_dyn(u16* __restrict__ sim, const int* __restrict__ kinfo) {
  const int kp = kinfo[1];
  const int row = blockIdx.x;
  uint4* r = (uint4*)(sim + (size_t)row * BATCH);
  float v[32];
  int active[4];
  float mx = -3.0e38f;
#pragma unroll
  for (int ch = 0; ch < 4; ch++) {
    int base = ch * 2048 + threadIdx.x * 8;
    active[ch] = (base < kp);
    if (active[ch]) {
      uint4 d = r[ch * 256 + threadIdx.x];
      const u16* u = (const u16*)&d;
#pragma unroll
      for (int j = 0; j < 8; j++) {
        float f = bf2f(u[j]);
        v[ch * 8 + j] = f;
        mx = fmaxf(mx, f);
      }
    }
  }
  __shared__ float red[256];
  red[threadIdx.x] = mx;
  __syncthreads();
  for (int st = 128; st > 0; st >>= 1) {
    if ((int)threadIdx.x < st) red[threadIdx.x] = fmaxf(red[threadIdx.x], red[threadIdx.x + st]);
    __syncthreads();
  }
  mx = red[0];
  __syncthreads();
  float s = 0.f;
#pragma unroll
  for (int ch = 0; ch < 4; ch++) {
    if (active[ch]) {
#pragma unroll
      for (int j = 0; j < 8; j++) {
        float e = (v[ch * 8 + j] < -1.0e30f) ? 0.f : __expf(v[ch * 8 + j] - mx);
        v[ch * 8 + j] = e;
        s += e;
      }
    }
  }
  red[threadIdx.x] = s;
  __syncthreads();
  for (int st = 128; st > 0; st >>= 1) {
    if ((int)threadIdx.x < st) red[threadIdx.x] += red[threadIdx.x + st];
    __syncthreads();
  }
  float inv = (red[0] > 0.f) ? 1.0f / red[0] : 0.f;
#pragma unroll
  for (int ch = 0; ch < 4; ch++) {
    if (active[ch]) {
      uint4 d;
      u16* u = (u16*)&d;
#pragma unroll
      for (int j = 0; j < 8; j++) u[j] = f2bf(v[ch * 8 + j] * inv);
      r[ch * 256 + threadIdx.x] = d;
    }
  }
}

enum { EPI_BF16 = 0, EPI_SIM = 1, EPI_F32 = 2, EPI_GELU = 3, EPI_FINAL = 4 };

__device__ __forceinline__ void async_load16(const u16* g, u16* l) {
  __builtin_amdgcn_global_load_lds(
      (const __attribute__((address_space(1))) void*)g,
      (__attribute__((address_space(3))) void*)l, 16, 0, 0);
}

// ============================================================================
// gemm256 v2: C[M][N] = A[M][K] @ B[N][K]^T, 256x256 tile, BK=32, 512 thr
// (8 waves 2Mx4N), per-wave 128x64 via 8x4 mfma_f32_16x16x32_bf16.
//
// Invariant ledger (audited):
//  - LDS ring: 4 slots x 32KB (A 16KB | B 16KB). Tile t -> slot t&3.
//  - Phases: per K-tile t two phases. P(t,0): MFMA(a0,b0)->acc[0..3], pre-read
//    a1<-A(t)hi, stage A(t+3). P(t,1): MFMA(a1,b0)->acc[4..7], pre-read
//    a0<-A(t+1)lo + b'<-B(t+1), stage B(t+3). Register ping-pong b0/b1 with
//    period 2 tiles; t-loop unrolled by 2 so ALL register indices are static.
//  - lgkmcnt chain: phases issue 4 (phase0) or 8 (phase1) ds_reads; each phase
//    waits ONLY the previous phase's reads: lgkmcnt(4) in phase0 (own 4 stay),
//    lgkmcnt(8) in phase1 (own 8 stay); tail phase with no own reads uses
//    lgkmcnt(0). Own reads drain on the LDS pipe DURING the MFMA cluster.
//    (global_load_lds counts vmcnt only, so stages don't perturb lgkmcnt.)
//  - Residency: vmcnt(6) at end of each phase0 (+barrier) => loads of tiles
//    <= t+1 done device-wide (6 = A,B of t+2 + A of t+3 still in flight);
//    tail chain 6->4->0->skip. P(t,1)'s pre-read of tile t+1 comes after.
//  - Slot reuse: stage X(t+3) writes slot (t-1)&3. All reads of tile t-1 were
//    issued by P(t-1,0) and completed per-wave by P(t-1,1)'s lgkmcnt (which
//    precedes its MFMA), hence device-wide by the end-of-P(t-1,1) barrier,
//    which precedes P(t,0)'s stage. One barrier per phase suffices.
//  - Prologue: stage tiles 0..2 (12 loads), vmcnt(8) -> tile 0 resident,
//    barrier, pre-read a0/b0 (8 ds_reads) for P(0,0).
//  - NT = Keff/32 is always even (K multiple of 64 at every call site).
//  - LDS image: st_16x32 swizzle, swz(x)=x^(((x>>9)&1)<<5); linear LDS dest +
//    pre-swizzled global source (both-sides-or-neither); read XOR cancels.
//  - Accumulation k-order identical to v1 (numerics unchanged).
// ============================================================================
template <int EPI>
__global__ __launch_bounds__(512, 2) void gemm256(
    const u16* __restrict__ A, int lda,
    const u16* __restrict__ B, int ldb,
    void* __restrict__ C, int ldc,
    int M, int N, int K,
    const int* __restrict__ kinfo, int dynN, int dynK,
    const int* __restrict__ idxc,
    const float* __restrict__ aux,
    const u16* __restrict__ aux2,
    const float* __restrict__ bias) {
  // bijective XCD-aware block swizzle (T1, m204 formula)
  const int nwg = (int)(gridDim.x * gridDim.y);
  const int orig = (int)(blockIdx.y * gridDim.x + blockIdx.x);
  int wgid;
  {
    int q = nwg >> 3, r = nwg & 7, x = orig & 7, lo = orig >> 3;
    wgid = (x < r ? x * (q + 1) : r * (q + 1) + (x - r) * q) + lo;
  }
  const int bx = wgid % (int)gridDim.x;
  const int by = wgid / (int)gridDim.x;
  const int rowBase = by * 256;
  const int colBase = bx * 256;
  if (dynN && colBase >= kinfo[1]) return;  // block-uniform, precedes all barriers
  const int Keff = dynK ? kinfo[1] : K;
  const int NT = Keff >> 5;  // K-tiles of 32; always even

  __shared__ __align__(16) u16 sm[4 * 16384];  // 4 slots x (A 8192 + B 8192) u16

  const int tid = threadIdx.x;
  const int lane = tid & 63, wave = tid >> 6;
  const int wm = wave >> 2, wn = wave & 3;   // 2M x 4N
  const int fr = lane & 15, kq = lane >> 4;  // frag row / k-chunk

  // frag LDS byte offsets (slot-relative, constant across tiles)
  int aOff[8], bOff[4];
#pragma unroll
  for (int mi = 0; mi < 8; mi++) {
    int lin = ((wm * 8 + mi) << 10) + (fr << 6) + (kq << 4);
    aOff[mi] = lin ^ (((fr >> 3) & 1) << 5);
  }
#pragma unroll
  for (int ni = 0; ni < 4; ni++) {
    int lin = ((wn * 4 + ni) << 10) + (fr << 6) + (kq << 4);
    bOff[ni] = (lin ^ (((fr >> 3) & 1) << 5)) + 16384;  // B half of slot (+16KB)
  }

  // staging coords (pre-swizzled global source, linear LDS dest)
  const int i0row = wave * 16 + (lane >> 2);                        // + i*128
  const int scol = ((lane & 3) << 3) ^ (((lane >> 5) & 1) << 4);    // 8-aligned

  auto stageA = [&](int tt) {
    const int sb = (tt & 3) * 16384;
    const int kt = tt << 5;
#pragma unroll
    for (int i = 0; i < 2; i++)
      async_load16(A + (size_t)(rowBase + i * 128 + i0row) * lda + kt + scol,
                   sm + sb + i * 4096 + tid * 8);
  };
  auto stageB = [&](int tt) {
    const int sb = (tt & 3) * 16384 + 8192;
    const int kt = tt << 5;
#pragma unroll
    for (int i = 0; i < 2; i++)
      async_load16(B + (size_t)(colBase + i * 128 + i0row) * ldb + kt + scol,
                   sm + sb + i * 4096 + tid * 8);
  };

  f32x4 zero = {0.f, 0.f, 0.f, 0.f};
  f32x4 acc[8][4];
#pragma unroll
  for (int mi = 0; mi < 8; mi++)
#pragma unroll
    for (int ni = 0; ni < 4; ni++) acc[mi][ni] = zero;

  // ---- prologue: stage tiles 0..2; tile 0 resident; pre-read P(0,0) operands
  if (NT > 0) { stageA(0); stageB(0); }
  if (NT > 1) { stageA(1); stageB(1); }
  if (NT > 2) { stageA(2); stageB(2); }
  if (NT > 2)      asm volatile("s_waitcnt vmcnt(8)" ::: "memory");
  else if (NT > 1) asm volatile("s_waitcnt vmcnt(4)" ::: "memory");
  else             asm volatile("s_waitcnt vmcnt(0)" ::: "memory");
  __builtin_amdgcn_sched_barrier(0);
  __builtin_amdgcn_s_barrier();

  bf16x8 a0[4], a1[4], b0[4], b1[4];
  {
    const char* s0 = (const char*)sm;
#pragma unroll
    for (int mi = 0; mi < 4; mi++) a0[mi] = *(const bf16x8*)(s0 + aOff[mi]);
#pragma unroll
    for (int ni = 0; ni < 4; ni++) b0[ni] = *(const bf16x8*)(s0 + bOff[ni]);
  }

#define MFMA_QUAD(AF, BF, OFS)                                                        \
  __builtin_amdgcn_s_setprio(1);                                                      \
  _Pragma("unroll") for (int mi = 0; mi < 4; mi++)                                    \
      _Pragma("unroll") for (int ni = 0; ni < 4; ni++)                                \
          acc[mi + OFS][ni] =                                                         \
              __builtin_amdgcn_mfma_f32_16x16x32_bf16(AF[mi], BF[ni], acc[mi + OFS][ni], 0, 0, 0); \
  __builtin_amdgcn_s_setprio(0);

  for (int t = 0; t < NT; t += 2) {
    const char* sT  = (const char*)sm + (size_t)((t    ) & 3) * 32768;
    const char* sT1 = (const char*)sm + (size_t)((t + 1) & 3) * 32768;
    const char* sT2 = (const char*)sm + (size_t)((t + 2) & 3) * 32768;

    // ---- P(t,0): pre-read a1<-A(t)hi; stage A(t+3); MFMA(a0,b0); vmcnt; bar
#pragma unroll
    for (int mi = 0; mi < 4; mi++) a1[mi] = *(const bf16x8*)(sT + aOff[mi + 4]);
    if (t + 3 < NT) stageA(t + 3);
    asm volatile("s_waitcnt lgkmcnt(4)" ::: "memory");
    __builtin_amdgcn_sched_barrier(0);
    MFMA_QUAD(a0, b0, 0)
    if (t + 3 < NT)      asm volatile("s_waitcnt vmcnt(6)" ::: "memory");
    else if (t + 2 < NT) asm volatile("s_waitcnt vmcnt(4)" ::: "memory");
    else if (t + 1 < NT) asm volatile("s_waitcnt vmcnt(0)" ::: "memory");
    __builtin_amdgcn_sched_barrier(0);
    __builtin_amdgcn_s_barrier();

    // ---- P(t,1): pre-read a0<-A(t+1)lo, b1<-B(t+1); stage B(t+3); MFMA(a1,b0); bar
    // (t+1 < NT always: NT even)
#pragma unroll
    for (int mi = 0; mi < 4; mi++) a0[mi] = *(const bf16x8*)(sT1 + aOff[mi]);
#pragma unroll
    for (int ni = 0; ni < 4; ni++) b1[ni] = *(const bf16x8*)(sT1 + bOff[ni]);
    if (t + 3 < NT) stageB(t + 3);
    asm volatile("s_waitcnt lgkmcnt(8)" ::: "memory");
    __builtin_amdgcn_sched_barrier(0);
    MFMA_QUAD(a1, b0, 4)
    __builtin_amdgcn_s_barrier();

    // ---- P(t+1,0): pre-read a1<-A(t+1)hi; stage A(t+4); MFMA(a0,b1); vmcnt; bar
#pragma unroll
    for (int mi = 0; mi < 4; mi++) a1[mi] = *(const bf16x8*)(sT1 + aOff[mi + 4]);
    if (t + 4 < NT) stageA(t + 4);
    asm volatile("s_waitcnt lgkmcnt(4)" ::: "memory");
    __builtin_amdgcn_sched_barrier(0);
    MFMA_QUAD(a0, b1, 0)
    if (t + 4 < NT)      asm volatile("s_waitcnt vmcnt(6)" ::: "memory");
    else if (t + 3 < NT) asm volatile("s_waitcnt vmcnt(4)" ::: "memory");
    else if (t + 2 < NT) asm volatile("s_waitcnt vmcnt(0)" ::: "memory");
    __builtin_amdgcn_sched_barrier(0);
    __builtin_amdgcn_s_barrier();

    // ---- P(t+1,1): pre-read a0<-A(t+2)lo, b0<-B(t+2) (if exists); stage B(t+4);
    //      MFMA(a1,b1); bar
    if (t + 2 < NT) {
#pragma unroll
      for (int mi = 0; mi < 4; mi++) a0[mi] = *(const bf16x8*)(sT2 + aOff[mi]);
#pragma unroll
      for (int ni = 0; ni < 4; ni++) b0[ni] = *(const bf16x8*)(sT2 + bOff[ni]);
    }
    if (t + 4 < NT) stageB(t + 4);
    if (t + 2 < NT) asm volatile("s_waitcnt lgkmcnt(8)" ::: "memory");
    else            asm volatile("s_waitcnt lgkmcnt(0)" ::: "memory");
    __builtin_amdgcn_sched_barrier(0);
    MFMA_QUAD(a1, b1, 4)
    __builtin_amdgcn_s_barrier();
  }
#undef MFMA_QUAD

  // Epilogue. C/D layout: col = lane&15, row = (lane>>4)*4 + reg  [m89-verified]
  const int quad = lane >> 4, lcol = lane & 15;
#pragma unroll
  for (int mi = 0; mi < 8; mi++) {
#pragma unroll
    for (int ni = 0; ni < 4; ni++) {
#pragma unroll
      for (int r = 0; r < 4; r++) {
        int grow = rowBase + wm * 128 + mi * 16 + quad * 4 + r;
        int gcol = colBase + wn * 64 + ni * 16 + lcol;
        float v = acc[mi][ni][r];
        size_t idx = (size_t)grow * ldc + gcol;
        if constexpr (EPI == EPI_BF16) {
          ((u16*)C)[idx] = f2bf(v);
        } else if constexpr (EPI == EPI_SIM) {
          bool dead = (gcol >= kinfo[0]) || (idxc[gcol] == grow);
          ((u16*)C)[idx] = dead ? (u16)0xFF80 : f2bf(v);
        } else if constexpr (EPI == EPI_F32) {
          ((float*)C)[idx] = v;
        } else if constexpr (EPI == EPI_GELU) {
          float x = v + aux[idx] + bias[gcol];
          float g = 0.5f * x * (1.0f + erff(x * 0.70710678118654752f));
          ((u16*)C)[idx] = f2bf(g);
        } else {  // EPI_FINAL
          float x = v + bias[gcol];
          float g = 1.0f / (1.0f + __expf(-x));
          ((float*)C)[idx] = aux[idx] + g * bf2f(aux2[idx]);
        }
      }
    }
  }
}

// ---------------- 128x128 m97-structure GEMM (kept for the N=1024 h1 passes) ----------------
template <int EPI>
__global__ __launch_bounds__(256) void gemm_bt(
    const u16* __restrict__ A, int lda,
    const u16* __restrict__ B, int ldb,
    void* __restrict__ C, int ldc,
    int M, int N, int K,
    const int* __restrict__ kinfo, int dynN, int dynK,
    const int* __restrict__ idxc,
    const float* __restrict__ aux,
    const u16* __restrict__ aux2,
    const float* __restrict__ bias) {
  const int rowBase = blockIdx.y * 128;
  const int colBase = blockIdx.x * 128;
  if (dynN && colBase >= kinfo[1]) return;
  const int Keff = dynK ? kinfo[1] : K;

  __shared__ __align__(16) u16 lA[128 * 64];
  __shared__ __align__(16) u16 lB[128 * 64];
  const int tid = threadIdx.x;
  const int lane = tid & 63;
  const int wave = tid >> 6;
  const int waveRow = (wave >> 1) * 64;
  const int waveCol = (wave & 1) * 64;

  const u16* Ab = A + (size_t)rowBase * lda;
  const u16* Bb = B + (size_t)colBase * ldb;

  f32x4 zero = {0.f, 0.f, 0.f, 0.f};
  f32x4 acc[4][4];
#pragma unroll
  for (int mi = 0; mi < 4; mi++)
#pragma unroll
    for (int ni = 0; ni < 4; ni++) acc[mi][ni] = zero;

  for (int kt = 0; kt < Keff; kt += 64) {
#pragma unroll
    for (int i = 0; i < 4; i++) {
      int c = i * 256 + tid;
      int row = c >> 3, k8 = c & 7;
      int gk8 = k8 ^ (row & 7);
      async_load16(Ab + (size_t)row * lda + kt + gk8 * 8, &lA[c * 8]);
    }
#pragma unroll
    for (int i = 0; i < 4; i++) {
      int c = i * 256 + tid;
      int row = c >> 3, k8 = c & 7;
      int gk8 = k8 ^ (row & 7);
      async_load16(Bb + (size_t)row * ldb + kt + gk8 * 8, &lB[c * 8]);
    }
    __syncthreads();
#pragma unroll
    for (int ks = 0; ks < 2; ks++) {
      const int kq = ks * 4 + (lane >> 4);
      bf16x8 af[4], bfr[4];
#pragma unroll
      for (int mi = 0; mi < 4; mi++) {
        int row = waveRow + mi * 16 + (lane & 15);
        af[mi] = *(const bf16x8*)&lA[row * 64 + ((kq ^ (row & 7)) * 8)];
      }
#pragma unroll
      for (int ni = 0; ni < 4; ni++) {
        int row = waveCol + ni * 16 + (lane & 15);
        bfr[ni] = *(const bf16x8*)&lB[row * 64 + ((kq ^ (row & 7)) * 8)];
      }
#pragma unroll
      for (int mi = 0; mi < 4; mi++)
#pragma unroll
        for (int ni = 0; ni < 4; ni++)
          acc[mi][ni] = __builtin_amdgcn_mfma_f32_16x16x32_bf16(af[mi], bfr[ni], acc[mi][ni], 0, 0, 0);
    }
    __syncthreads();
  }

  const int quad = lane >> 4, lcol = lane & 15;
#pragma unroll
  for (int mi = 0; mi < 4; mi++) {
#pragma unroll
    for (int ni = 0; ni < 4; ni++) {
#pragma unroll
      for (int r = 0; r < 4; r++) {
        int grow = rowBase + waveRow + mi * 16 + quad * 4 + r;
        int gcol = colBase + waveCol + ni * 16 + lcol;
        float v = acc[mi][ni][r];
        size_t idx = (size_t)grow * ldc + gcol;
        if constexpr (EPI == EPI_BF16) {
          ((u16*)C)[idx] = f2bf(v);
        } else if constexpr (EPI == EPI_SIM) {
          bool dead = (gcol >= kinfo[0]) || (idxc[gcol] == grow);
          ((u16*)C)[idx] = dead ? (u16)0xFF80 : f2bf(v);
        } else if constexpr (EPI == EPI_F32) {
          ((float*)C)[idx] = v;
        } else if constexpr (EPI == EPI_GELU) {
          float x = v + aux[idx] + bias[gcol];
          float g = 0.5f * x * (1.0f + erff(x * 0.70710678118654752f));
          ((u16*)C)[idx] = f2bf(g);
        } else {
          float x = v + bias[gcol];
          float g = 1.0f / (1.0f + __expf(-x));
          ((float*)C)[idx] = aux[idx] + g * bf2f(aux2[idx]);
        }
      }
    }
  }
}

// ---------------- host launch ----------------
extern "C" void kernel_launch(void* const* d_in, const int* in_sizes, int n_in,
                              void* d_out, int out_size, void* d_ws, size_t ws_size,
                              hipStream_t stream) {
  const float* hs   = (const float*)d_in[0];
  const void*  mraw = d_in[1];
  const float* Wsim = (const float*)d_in[2];
  const float* Wval = (const float*)d_in[3];
  const float* Wg1  = (const float*)d_in[4];
  const float* bg1  = (const float*)d_in[5];
  const float* Wg2  = (const float*)d_in[6];
  const float* bg2  = (const float*)d_in[7];
  float* out = (float*)d_out;

  char* ws = (char*)d_ws;
  size_t off = 0;
  auto alloc = [&](size_t bytes) {
    char* p = ws + off;
    off += (bytes + 255) & ~(size_t)255;
    return p;
  };
  u16* hidden_bf = (u16*)alloc((size_t)BATCH * HDIM * 2);
  u16* wbuf      = (u16*)alloc((size_t)HDIM * HDIM * 2);
  u16* r1        = (u16*)alloc((size_t)BATCH * HDIM * 2);
  u16* r2        = (u16*)alloc((size_t)BATCH * HDIM * 2);
  int* idxc      = (int*)alloc((size_t)BATCH * 4);
  int* kinfo     = (int*)alloc(256);
  int* flag      = (int*)alloc(256);
  if (off > ws_size) return;

  u16*   simw  = (u16*)d_out;
  float* h1acc = (float*)d_out;
  (void)in_sizes; (void)n_in; (void)out_size;

  dim3 blk(256);
  dim3 blk5(512);

  detect_mask<<<1, 256, 0, stream>>>((const unsigned char*)mraw, BATCH, flag);
  compact_mask<<<1, 256, 0, stream>>>(mraw, flag, idxc, kinfo);

  cast_f32_bf16<<<(BATCH * HDIM / 4) / 256, 256, 0, stream>>>(hs, hidden_bf, BATCH * HDIM / 4);

  // proj = hidden @ Wsim^T  [B, H] -> r1
  cast_f32_bf16<<<(HDIM * HDIM / 4) / 256, 256, 0, stream>>>(Wsim, wbuf, HDIM * HDIM / 4);
  gemm256<EPI_BF16><<<dim3(HDIM / 256, BATCH / 256), blk5, 0, stream>>>(
      hidden_bf, HDIM, wbuf, HDIM, r1, HDIM, BATCH, HDIM, HDIM,
      nullptr, 0, 0, nullptr, nullptr, nullptr, nullptr);
  normalize_rows<<<BATCH, 256, 0, stream>>>(r1);

  gather_rows<<<BATCH, 256, 0, stream>>>(r1, r2, idxc, kinfo);

  // sim = normed @ normed_c^T  [B, kc_pad] (ld=BATCH) -> simw
  gemm256<EPI_SIM><<<dim3(BATCH / 256, BATCH / 256), blk5, 0, stream>>>(
      r1, HDIM, r2, HDIM, simw, BATCH, BATCH, BATCH, HDIM,
      kinfo, 1, 0, idxc, nullptr, nullptr, nullptr);
  softmax_rows_dyn<<<BATCH, 256, 0, stream>>>(simw, kinfo);

  gather_rows<<<BATCH, 256, 0, stream>>>(hidden_bf, r1, idxc, kinfo);

  // valuesT_c = Wval @ hidden_c^T  [H, kc_pad] (ld=BATCH) -> r2
  cast_f32_bf16<<<(HDIM * HDIM / 4) / 256, 256, 0, stream>>>(Wval, wbuf, HDIM * HDIM / 4);
  gemm256<EPI_BF16><<<dim3(BATCH / 256, HDIM / 256), blk5, 0, stream>>>(
      wbuf, HDIM, r1, HDIM, r2, BATCH, HDIM, BATCH, HDIM,
      kinfo, 1, 0, nullptr, nullptr, nullptr, nullptr);

  // cross = weights_c @ valuesT_c^T  [B, H], K = kc_pad -> r1
  gemm256<EPI_BF16><<<dim3(HDIM / 256, BATCH / 256), blk5, 0, stream>>>(
      simw, BATCH, r2, BATCH, r1, HDIM, BATCH, HDIM, BATCH,
      kinfo, 0, 1, nullptr, nullptr, nullptr, nullptr);

  // h1 pass 1: hidden @ Wg1[:, :H]^T -> fp32 acc (d_out)  [B, GH]
  cast_f32_bf16<<<(GHDIM * 2 * HDIM / 4) / 256, 256, 0, stream>>>(Wg1, wbuf, GHDIM * 2 * HDIM / 4);
  gemm_bt<EPI_F32><<<dim3(GHDIM / 128, BATCH / 128), blk, 0, stream>>>(
      hidden_bf, HDIM, wbuf, 2 * HDIM, h1acc, GHDIM, BATCH, GHDIM, HDIM,
      nullptr, 0, 0, nullptr, nullptr, nullptr, nullptr);
  // h1 pass 2: + cross @ Wg1[:, H:]^T, + b_g1, exact GELU -> r2
  gemm_bt<EPI_GELU><<<dim3(GHDIM / 128, BATCH / 128), blk, 0, stream>>>(
      r1, HDIM, wbuf + HDIM, 2 * HDIM, r2, GHDIM, BATCH, GHDIM, HDIM,
      nullptr, 0, 0, nullptr, h1acc, nullptr, bg1);

  // out = hidden + sigmoid(h1 @ Wg2^T + b_g2) * cross  [B, H] fp32 -> d_out
  cast_f32_bf16<<<(HDIM * GHDIM / 4) / 256, 256, 0, stream>>>(Wg2, wbuf, HDIM * GHDIM / 4);
  gemm256<EPI_FINAL><<<dim3(HDIM / 256, BATCH / 256), blk5, 0, stream>>>(
      r2, GHDIM, wbuf, GHDIM, out, HDIM, BATCH, HDIM, GHDIM,
      nullptr, 0, 0, nullptr, hs, r1, bg2);
}

// Round 4
// 1799.810 us; speedup vs baseline: 1.1272x; 1.0044x over previous
//
#include <hip/hip_runtime.h>

// CrossBatchEmbeddingMixer: B=8192, H=4096, GH=1024, TEMP=1
// bf16 MFMA GEMMs, fp32 accumulate, fused epilogues.
// gemm256 v3: faithful m201-style 8-phase schedule. BK=64, 4 quadrant-phases
// per K-tile (each = one 128x128 C-quadrant, 16 MFMA), A/B fragment register
// reuse across phases (12/4/8/0 ds_reads), half-tile staging stream with
// counted vmcnt(6) once per K-tile (never 0 in main loop), ring-5 half-slots
// per operand (160 KB LDS), st-style XOR swizzle with pre-swizzled
// global_load_lds sources. NO sched_barrier(0) in the loop (m141 lesson).
// h1 GEMMs (N=1024) stay on the 128^2 kernel (grid fit: 512 vs 128 blocks).

#define HDIM 4096
#define BATCH 8192
#define GHDIM 1024

typedef unsigned short u16;
typedef short bf16x8 __attribute__((ext_vector_type(8)));
typedef float f32x4 __attribute__((ext_vector_type(4)));

__device__ __forceinline__ u16 f2bf(float f) {
  union { float f; unsigned u; } v; v.f = f;
  unsigned r = v.u + 0x7FFFu + ((v.u >> 16) & 1u);
  return (u16)(r >> 16);
}
__device__ __forceinline__ float bf2f(u16 u) {
  union { unsigned u; float f; } v; v.u = ((unsigned)u) << 16;
  return v.f;
}

// ---------------- cast fp32 -> bf16 (vectorized) ----------------
__global__ void cast_f32_bf16(const float* __restrict__ src, u16* __restrict__ dst, int n4) {
  int i = blockIdx.x * 256 + threadIdx.x;
  if (i < n4) {
    float4 f = ((const float4*)src)[i];
    ushort4 o;
    o.x = f2bf(f.x); o.y = f2bf(f.y); o.z = f2bf(f.z); o.w = f2bf(f.w);
    ((ushort4*)dst)[i] = o;
  }
}

// ---------------- mask canonicalization ----------------
__global__ void detect_mask(const unsigned char* __restrict__ m, int nbytes, int* __restrict__ flag) {
  __shared__ int cnt[256];
  int c = 0;
  for (int i = threadIdx.x; i < nbytes; i += 256)
    if ((i & 3) && m[i]) c++;
  cnt[threadIdx.x] = c;
  __syncthreads();
  for (int s = 128; s > 0; s >>= 1) {
    if ((int)threadIdx.x < s) cnt[threadIdx.x] += cnt[threadIdx.x + s];
    __syncthreads();
  }
  if (threadIdx.x == 0) *flag = cnt[0];
}

// ---------------- compact valid column indices ----------------
// kinfo[0]=kc, kinfo[1]=kc rounded up to 256 (256-tile-aligned for gemm256).
__global__ void compact_mask(const void* __restrict__ raw, const int* __restrict__ flag,
                             int* __restrict__ idxc, int* __restrict__ kinfo) {
  const int t = threadIdx.x;
  const bool isbool = (*flag > 0);
  __shared__ int cnt[256];
  __shared__ int total;
  const int base0 = t * 32;
  int c = 0;
  for (int i = 0; i < 32; i++) {
    int gi = base0 + i;
    int v = isbool ? ((const unsigned char*)raw)[gi] : ((const int*)raw)[gi];
    if (v) c++;
  }
  cnt[t] = c;
  __syncthreads();
  if (t == 0) {
    int acc = 0;
    for (int i = 0; i < 256; i++) { int x = cnt[i]; cnt[i] = acc; acc += x; }
    total = acc;
    kinfo[0] = acc;
    kinfo[1] = (acc + 255) & ~255;
  }
  __syncthreads();
  int w = cnt[t];
  for (int i = 0; i < 32; i++) {
    int gi = base0 + i;
    int v = isbool ? ((const unsigned char*)raw)[gi] : ((const int*)raw)[gi];
    if (v) idxc[w++] = gi;
  }
  for (int i = total + t; i < BATCH; i += 256) idxc[i] = -1;
}

// ---------------- gather valid rows [kc_pad, H], zero-fill pad rows ----------------
__global__ void gather_rows(const u16* __restrict__ src, u16* __restrict__ dst,
                            const int* __restrict__ idxc, const int* __restrict__ kinfo) {
  int c = blockIdx.x;
  int kc = kinfo[0], kp = kinfo[1];
  if (c >= kp) return;
  uint4* d = (uint4*)(dst + (size_t)c * HDIM);
  if (c < kc) {
    const uint4* s = (const uint4*)(src + (size_t)idxc[c] * HDIM);
    d[threadIdx.x] = s[threadIdx.x];
    d[threadIdx.x + 256] = s[threadIdx.x + 256];
  } else {
    uint4 z = {0, 0, 0, 0};
    d[threadIdx.x] = z;
    d[threadIdx.x + 256] = z;
  }
}

// ---------------- row L2-normalize (in place, bf16 [BATCH][HDIM]) ----------------
__global__ void normalize_rows(u16* __restrict__ p) {
  int row = blockIdx.x;
  uint4* r = (uint4*)(p + (size_t)row * HDIM);
  uint4 d[2];
  float s = 0.f;
#pragma unroll
  for (int i = 0; i < 2; i++) {
    d[i] = r[i * 256 + threadIdx.x];
    const u16* u = (const u16*)&d[i];
#pragma unroll
    for (int j = 0; j < 8; j++) { float f = bf2f(u[j]); s += f * f; }
  }
  __shared__ float red[256];
  red[threadIdx.x] = s;
  __syncthreads();
  for (int st = 128; st > 0; st >>= 1) {
    if ((int)threadIdx.x < st) red[threadIdx.x] += red[threadIdx.x + st];
    __syncthreads();
  }
  float scale = 1.0f / fmaxf(sqrtf(red[0]), 1e-12f);
#pragma unroll
  for (int i = 0; i < 2; i++) {
    u16* u = (u16*)&d[i];
#pragma unroll
    for (int j = 0; j < 8; j++) u[j] = f2bf(bf2f(u[j]) * scale);
    r[i * 256 + threadIdx.x] = d[i];
  }
}

// ---------------- row softmax over kc_pad compacted cols (in place, ld=BATCH) ----------------
__global__ void softmax_rows_dyn(u16* __restrict__ sim, const int* __restrict__ kinfo) {
  const int kp = kinfo[1];
  const int row = blockIdx.x;
  uint4* r = (uint4*)(sim + (size_t)row * BATCH);
  float v[32];
  int active[4];
  float mx = -3.0e38f;
#pragma unroll
  for (int ch = 0; ch < 4; ch++) {
    int base = ch * 2048 + threadIdx.x * 8;
    active[ch] = (base < kp);
    if (active[ch]) {
      uint4 d = r[ch * 256 + threadIdx.x];
      const u16* u = (const u16*)&d;
#pragma unroll
      for (int j = 0; j < 8; j++) {
        float f = bf2f(u[j]);
        v[ch * 8 + j] = f;
        mx = fmaxf(mx, f);
      }
    }
  }
  __shared__ float red[256];
  red[threadIdx.x] = mx;
  __syncthreads();
  for (int st = 128; st > 0; st >>= 1) {
    if ((int)threadIdx.x < st) red[threadIdx.x] = fmaxf(red[threadIdx.x], red[threadIdx.x + st]);
    __syncthreads();
  }
  mx = red[0];
  __syncthreads();
  float s = 0.f;
#pragma unroll
  for (int ch = 0; ch < 4; ch++) {
    if (active[ch]) {
#pragma unroll
      for (int j = 0; j < 8; j++) {
        float e = (v[ch * 8 + j] < -1.0e30f) ? 0.f : __expf(v[ch * 8 + j] - mx);
        v[ch * 8 + j] = e;
        s += e;
      }
    }
  }
  red[threadIdx.x] = s;
  __syncthreads();
  for (int st = 128; st > 0; st >>= 1) {
    if ((int)threadIdx.x < st) red[threadIdx.x] += red[threadIdx.x + st];
    __syncthreads();
  }
  float inv = (red[0] > 0.f) ? 1.0f / red[0] : 0.f;
#pragma unroll
  for (int ch = 0; ch < 4; ch++) {
    if (active[ch]) {
      uint4 d;
      u16* u = (u16*)&d;
#pragma unroll
      for (int j = 0; j < 8; j++) u[j] = f2bf(v[ch * 8 + j] * inv);
      r[ch * 256 + threadIdx.x] = d;
    }
  }
}

enum { EPI_BF16 = 0, EPI_SIM = 1, EPI_F32 = 2, EPI_GELU = 3, EPI_FINAL = 4 };

__device__ __forceinline__ void async_load16(const u16* g, u16* l) {
  __builtin_amdgcn_global_load_lds(
      (const __attribute__((address_space(1))) void*)g,
      (__attribute__((address_space(3))) void*)l, 16, 0, 0);
}

// ============================================================================
// gemm256 v3: C[M][N] = A[M][K] @ B[N][K]^T, 256x256 tile, BK=64, 512 thr
// (8 waves 2Mx4N within each quadrant).
//
// Schedule (m201-faithful; invariant ledger audited):
//  - K-tile = 64. A-tile 256x64 = 2 halves (rows 0-127 / 128-255) of 16 KB;
//    B-tile likewise. LDS: ring-5 half-slots per operand = 10 x 16 KB = 160 KB.
//  - Group g (4 phases) computes tile g. Phase q = one 128x128 C-quadrant,
//    pairing (Ah,Bh): q0=(A0,B0) q1=(A0,B1) q2=(A1,B0) q3=(A1,B1).
//    All 8 waves split each quadrant 2Mx4N -> 64x32 per wave -> 16 MFMA.
//    A-frags reused q0->q1 and q2->q3; B0-frags live q0->q2, B1 q1->q3.
//    ds_reads per phase per wave: 12 / 4 / 8 / 0.
//  - Phase body (template-verbatim): reads (plain derefs); 1 half-tile stage
//    (2 x global_load_lds); [lgkmcnt(8) when 12 reads]; s_barrier;
//    lgkmcnt(0); setprio(1); 16 MFMA; setprio(0); s_barrier.
//    No sched_barrier(0); only the per-tile vmcnt carries a "memory" clobber.
//  - Stage stream (1 half/phase): q0: B1(g+1); q1: A0(g+2); q2: B0(g+2);
//    q3: A1(g+2). Boundary vmcnt(6) after q3's MFMA => only {A0,B0,A1}(g+2)
//    in flight => tile g+1 fully resident before group g+1. Never 0 in main
//    loop; tail: vmcnt(0) once before the last group.
//  - Slot ring (per operand, 5 slots): half seq a = 2t+j -> slot a%5. Group g
//    computes from slots s0=(2g)%5, s1=(2g+1)%5; stages to (s1+2)%5 [B1(g+1)],
//    (s0+4)%5 [A0/B0(g+2)], s0 [A1(g+2)]. Every reuse is >=2 barriers after
//    the previous occupant's last read (audited: A0(g) last read q1, slot
//    restaged q3; A1(g-1) last read q3(g-1), restaged q1(g); B0(g-1) last
//    read q2(g-1), restaged q0(g); B1(g-1) last read q3(g-1), restaged q2(g)).
//  - Prologue: stage A0,B0,A1,B1(0), A0,B0,A1(1) (14 loads), vmcnt(6) ->
//    tile 0 resident (oldest 8 loads drained), barrier.
//  - LDS image swizzle: half = 128 rows x 64 bf16; lin = R*128 + c16*16
//    (c16 = 16B chunk 0..7); stored at lin ^ ((R&7)<<4). global_load_lds
//    writes linearly at i*8192 + tid*16, so source element is pre-swizzled:
//    row = i*64 + (tid>>3), chunk = (tid ^ (tid>>3)) & 7. Read applies the
//    same XOR (involution). Bank audit: per ds_read_b128, 8 lanes/chunk
//    uniform over 8 chunks -> minimum bank touches (conflict-free).
//  - NT = Keff/64 (all call sites: K multiple of 256). Numerics: same k-order
//    as v2 (tiles ascending, 2 chained MFMA per 64-K per output).
// ============================================================================
template <int EPI>
__global__ __launch_bounds__(512, 2) void gemm256(
    const u16* __restrict__ A, int lda,
    const u16* __restrict__ B, int ldb,
    void* __restrict__ C, int ldc,
    int M, int N, int K,
    const int* __restrict__ kinfo, int dynN, int dynK,
    const int* __restrict__ idxc,
    const float* __restrict__ aux,
    const u16* __restrict__ aux2,
    const float* __restrict__ bias) {
  // bijective XCD-aware block swizzle (T1, m204 formula)
  const int nwg = (int)(gridDim.x * gridDim.y);
  const int orig = (int)(blockIdx.y * gridDim.x + blockIdx.x);
  int wgid;
  {
    int q = nwg >> 3, r = nwg & 7, x = orig & 7, lo = orig >> 3;
    wgid = (x < r ? x * (q + 1) : r * (q + 1) + (x - r) * q) + lo;
  }
  const int bx = wgid % (int)gridDim.x;
  const int by = wgid / (int)gridDim.x;
  const int rowBase = by * 256;
  const int colBase = bx * 256;
  if (dynN && colBase >= kinfo[1]) return;  // block-uniform, precedes all barriers
  const int Keff = dynK ? kinfo[1] : K;
  const int NT = Keff >> 6;  // K-tiles of 64 (NT multiple of 4 at all call sites)

  __shared__ __align__(16) u16 sm[81920];  // 160 KB: A ring 5x16KB @0, B ring @81920B

  const int tid = threadIdx.x;
  const int lane = tid & 63, wave = tid >> 6;
  const int wm = wave >> 2, wn = wave & 3;   // 2M x 4N within a quadrant
  const int fr = lane & 15, kq = lane >> 4;  // frag row / k-quad

  // frag LDS byte offsets within a half-slot (swizzled)
  int aO[4][2], bO[2][2];
#pragma unroll
  for (int mi = 0; mi < 4; mi++)
#pragma unroll
    for (int ks = 0; ks < 2; ks++) {
      int R = wm * 64 + mi * 16 + fr;
      int c16 = kq + ks * 4;
      aO[mi][ks] = (R << 7) + ((c16 ^ (R & 7)) << 4);
    }
#pragma unroll
  for (int ni = 0; ni < 2; ni++)
#pragma unroll
    for (int ks = 0; ks < 2; ks++) {
      int R = wn * 32 + ni * 16 + fr;
      int c16 = kq + ks * 4;
      bO[ni][ks] = (R << 7) + ((c16 ^ (R & 7)) << 4);
    }

  // staging: thread t writes half bytes [i*8192 + t*16); pre-swizzled source
  const int rT = tid >> 3;                         // 0..63 (+ i*64)
  const int cT = ((tid ^ (tid >> 3)) & 7) * 8;     // element col 0..56
  const u16* Abs = A + (size_t)(rowBase + rT) * lda + cT;
  const u16* Bbs = B + (size_t)(colBase + rT) * ldb + cT;

  auto stA = [&](int t, int h, int s) {  // half h of tile t -> A slot s
    const u16* src = Abs + (size_t)(h * 128) * lda + t * 64;
    u16* dst = sm + s * 8192 + tid * 8;
    async_load16(src, dst);
    async_load16(src + (size_t)64 * lda, dst + 4096);
  };
  auto stB = [&](int t, int h, int s) {
    const u16* src = Bbs + (size_t)(h * 128) * ldb + t * 64;
    u16* dst = sm + 40960 + s * 8192 + tid * 8;
    async_load16(src, dst);
    async_load16(src + (size_t)64 * ldb, dst + 4096);
  };

  f32x4 zero = {0.f, 0.f, 0.f, 0.f};
  f32x4 acc[4][4][2];  // [quadrant][mi][ni]
#pragma unroll
  for (int q = 0; q < 4; q++)
#pragma unroll
    for (int mi = 0; mi < 4; mi++)
#pragma unroll
      for (int ni = 0; ni < 2; ni++) acc[q][mi][ni] = zero;

  // ---- prologue: tile 0 (slots 0,1) + tile 1 A0,B0 (slot 2), A1 (slot 3)
  stA(0, 0, 0); stB(0, 0, 0); stA(0, 1, 1); stB(0, 1, 1);
  if (NT > 1) {
    stA(1, 0, 2); stB(1, 0, 2); stA(1, 1, 3);
    asm volatile("s_waitcnt vmcnt(6)" ::: "memory");
  } else {
    asm volatile("s_waitcnt vmcnt(0)" ::: "memory");
  }
  __builtin_amdgcn_s_barrier();

  bf16x8 aF[4][2], b0F[2][2], b1F[2][2];

#define MQUAD(Q, AF, BF)                                                       \
  __builtin_amdgcn_s_setprio(1);                                               \
  _Pragma("unroll") for (int mi = 0; mi < 4; mi++)                             \
  _Pragma("unroll") for (int ni = 0; ni < 2; ni++)                             \
  _Pragma("unroll") for (int ks = 0; ks < 2; ks++)                             \
      acc[Q][mi][ni] = __builtin_amdgcn_mfma_f32_16x16x32_bf16(                \
          AF[mi][ks], BF[ni][ks], acc[Q][mi][ni], 0, 0, 0);                    \
  __builtin_amdgcn_s_setprio(0);

  int s0 = 0, s1 = 1;  // slots of tile g's halves (same index for A and B rings)
  for (int g = 0; g < NT; ++g) {
    const char* smb = (const char*)sm;
    const int aB0 = s0 * 16384, aB1 = s1 * 16384;
    const int bB0 = 81920 + s0 * 16384, bB1 = 81920 + s1 * 16384;
    int sB1n = s1 + 2; if (sB1n >= 5) sB1n -= 5;  // B1(g+1)
    int sX2 = s0 + 4;  if (sX2 >= 5) sX2 -= 5;    // A0/B0(g+2)
    const int sA1n = s0;                           // A1(g+2)
    const bool st1 = (g + 1 < NT), st2 = (g + 2 < NT);

    // ---- q0: read A0(8) + B0(4); stage B1(g+1); MFMA (A0,B0)
#pragma unroll
    for (int mi = 0; mi < 4; mi++)
#pragma unroll
      for (int ks = 0; ks < 2; ks++) aF[mi][ks] = *(const bf16x8*)(smb + aB0 + aO[mi][ks]);
#pragma unroll
    for (int ni = 0; ni < 2; ni++)
#pragma unroll
      for (int ks = 0; ks < 2; ks++) b0F[ni][ks] = *(const bf16x8*)(smb + bB0 + bO[ni][ks]);
    if (st1) stB(g + 1, 1, sB1n);
    asm volatile("s_waitcnt lgkmcnt(8)");
    __builtin_amdgcn_s_barrier();
    asm volatile("s_waitcnt lgkmcnt(0)");
    MQUAD(0, aF, b0F)
    __builtin_amdgcn_s_barrier();

    // ---- q1: read B1(4); stage A0(g+2); MFMA (A0,B1)
#pragma unroll
    for (int ni = 0; ni < 2; ni++)
#pragma unroll
      for (int ks = 0; ks < 2; ks++) b1F[ni][ks] = *(const bf16x8*)(smb + bB1 + bO[ni][ks]);
    if (st2) stA(g + 2, 0, sX2);
    __builtin_amdgcn_s_barrier();
    asm volatile("s_waitcnt lgkmcnt(0)");
    MQUAD(1, aF, b1F)
    __builtin_amdgcn_s_barrier();

    // ---- q2: read A1(8); stage B0(g+2); MFMA (A1,B0)
#pragma unroll
    for (int mi = 0; mi < 4; mi++)
#pragma unroll
      for (int ks = 0; ks < 2; ks++) aF[mi][ks] = *(const bf16x8*)(smb + aB1 + aO[mi][ks]);
    if (st2) stB(g + 2, 0, sX2);
    __builtin_amdgcn_s_barrier();
    asm volatile("s_waitcnt lgkmcnt(0)");
    MQUAD(2, aF, b0F)
    __builtin_amdgcn_s_barrier();

    // ---- q3: no reads; stage A1(g+2); MFMA (A1,B1); boundary vmcnt
    if (st2) stA(g + 2, 1, sA1n);
    __builtin_amdgcn_s_barrier();
    MQUAD(3, aF, b1F)
    if (st2) asm volatile("s_waitcnt vmcnt(6)" ::: "memory");
    else     asm volatile("s_waitcnt vmcnt(0)" ::: "memory");
    __builtin_amdgcn_s_barrier();

    s0 += 2; if (s0 >= 5) s0 -= 5;
    s1 += 2; if (s1 >= 5) s1 -= 5;
  }
#undef MQUAD

  // Epilogue. C/D layout: col = lane&15, row = (lane>>4)*4 + reg  [m89-verified]
  const int quad = lane >> 4, lcol = lane & 15;
#pragma unroll
  for (int q = 0; q < 4; q++) {
#pragma unroll
    for (int mi = 0; mi < 4; mi++) {
#pragma unroll
      for (int ni = 0; ni < 2; ni++) {
#pragma unroll
        for (int r = 0; r < 4; r++) {
          int grow = rowBase + (q >> 1) * 128 + wm * 64 + mi * 16 + quad * 4 + r;
          int gcol = colBase + (q & 1) * 128 + wn * 32 + ni * 16 + lcol;
          float v = acc[q][mi][ni][r];
          size_t idx = (size_t)grow * ldc + gcol;
          if constexpr (EPI == EPI_BF16) {
            ((u16*)C)[idx] = f2bf(v);
          } else if constexpr (EPI == EPI_SIM) {
            bool dead = (gcol >= kinfo[0]) || (idxc[gcol] == grow);
            ((u16*)C)[idx] = dead ? (u16)0xFF80 : f2bf(v);
          } else if constexpr (EPI == EPI_F32) {
            ((float*)C)[idx] = v;
          } else if constexpr (EPI == EPI_GELU) {
            float x = v + aux[idx] + bias[gcol];
            float g = 0.5f * x * (1.0f + erff(x * 0.70710678118654752f));
            ((u16*)C)[idx] = f2bf(g);
          } else {  // EPI_FINAL
            float x = v + bias[gcol];
            float g = 1.0f / (1.0f + __expf(-x));
            ((float*)C)[idx] = aux[idx] + g * bf2f(aux2[idx]);
          }
        }
      }
    }
  }
}

// ---------------- 128x128 m97-structure GEMM (kept for the N=1024 h1 passes) ----------------
template <int EPI>
__global__ __launch_bounds__(256) void gemm_bt(
    const u16* __restrict__ A, int lda,
    const u16* __restrict__ B, int ldb,
    void* __restrict__ C, int ldc,
    int M, int N, int K,
    const int* __restrict__ kinfo, int dynN, int dynK,
    const int* __restrict__ idxc,
    const float* __restrict__ aux,
    const u16* __restrict__ aux2,
    const float* __restrict__ bias) {
  const int rowBase = blockIdx.y * 128;
  const int colBase = blockIdx.x * 128;
  if (dynN && colBase >= kinfo[1]) return;
  const int Keff = dynK ? kinfo[1] : K;

  __shared__ __align__(16) u16 lA[128 * 64];
  __shared__ __align__(16) u16 lB[128 * 64];
  const int tid = threadIdx.x;
  const int lane = tid & 63;
  const int wave = tid >> 6;
  const int waveRow = (wave >> 1) * 64;
  const int waveCol = (wave & 1) * 64;

  const u16* Ab = A + (size_t)rowBase * lda;
  const u16* Bb = B + (size_t)colBase * ldb;

  f32x4 zero = {0.f, 0.f, 0.f, 0.f};
  f32x4 acc[4][4];
#pragma unroll
  for (int mi = 0; mi < 4; mi++)
#pragma unroll
    for (int ni = 0; ni < 4; ni++) acc[mi][ni] = zero;

  for (int kt = 0; kt < Keff; kt += 64) {
#pragma unroll
    for (int i = 0; i < 4; i++) {
      int c = i * 256 + tid;
      int row = c >> 3, k8 = c & 7;
      int gk8 = k8 ^ (row & 7);
      async_load16(Ab + (size_t)row * lda + kt + gk8 * 8, &lA[c * 8]);
    }
#pragma unroll
    for (int i = 0; i < 4; i++) {
      int c = i * 256 + tid;
      int row = c >> 3, k8 = c & 7;
      int gk8 = k8 ^ (row & 7);
      async_load16(Bb + (size_t)row * ldb + kt + gk8 * 8, &lB[c * 8]);
    }
    __syncthreads();
#pragma unroll
    for (int ks = 0; ks < 2; ks++) {
      const int kq = ks * 4 + (lane >> 4);
      bf16x8 af[4], bfr[4];
#pragma unroll
      for (int mi = 0; mi < 4; mi++) {
        int row = waveRow + mi * 16 + (lane & 15);
        af[mi] = *(const bf16x8*)&lA[row * 64 + ((kq ^ (row & 7)) * 8)];
      }
#pragma unroll
      for (int ni = 0; ni < 4; ni++) {
        int row = waveCol + ni * 16 + (lane & 15);
        bfr[ni] = *(const bf16x8*)&lB[row * 64 + ((kq ^ (row & 7)) * 8)];
      }
#pragma unroll
      for (int mi = 0; mi < 4; mi++)
#pragma unroll
        for (int ni = 0; ni < 4; ni++)
          acc[mi][ni] = __builtin_amdgcn_mfma_f32_16x16x32_bf16(af[mi], bfr[ni], acc[mi][ni], 0, 0, 0);
    }
    __syncthreads();
  }

  const int quad = lane >> 4, lcol = lane & 15;
#pragma unroll
  for (int mi = 0; mi < 4; mi++) {
#pragma unroll
    for (int ni = 0; ni < 4; ni++) {
#pragma unroll
      for (int r = 0; r < 4; r++) {
        int grow = rowBase + waveRow + mi * 16 + quad * 4 + r;
        int gcol = colBase + waveCol + ni * 16 + lcol;
        float v = acc[mi][ni][r];
        size_t idx = (size_t)grow * ldc + gcol;
        if constexpr (EPI == EPI_BF16) {
          ((u16*)C)[idx] = f2bf(v);
        } else if constexpr (EPI == EPI_SIM) {
          bool dead = (gcol >= kinfo[0]) || (idxc[gcol] == grow);
          ((u16*)C)[idx] = dead ? (u16)0xFF80 : f2bf(v);
        } else if constexpr (EPI == EPI_F32) {
          ((float*)C)[idx] = v;
        } else if constexpr (EPI == EPI_GELU) {
          float x = v + aux[idx] + bias[gcol];
          float g = 0.5f * x * (1.0f + erff(x * 0.70710678118654752f));
          ((u16*)C)[idx] = f2bf(g);
        } else {
          float x = v + bias[gcol];
          float g = 1.0f / (1.0f + __expf(-x));
          ((float*)C)[idx] = aux[idx] + g * bf2f(aux2[idx]);
        }
      }
    }
  }
}

// ---------------- host launch ----------------
extern "C" void kernel_launch(void* const* d_in, const int* in_sizes, int n_in,
                              void* d_out, int out_size, void* d_ws, size_t ws_size,
                              hipStream_t stream) {
  const float* hs   = (const float*)d_in[0];
  const void*  mraw = d_in[1];
  const float* Wsim = (const float*)d_in[2];
  const float* Wval = (const float*)d_in[3];
  const float* Wg1  = (const float*)d_in[4];
  const float* bg1  = (const float*)d_in[5];
  const float* Wg2  = (const float*)d_in[6];
  const float* bg2  = (const float*)d_in[7];
  float* out = (float*)d_out;

  char* ws = (char*)d_ws;
  size_t off = 0;
  auto alloc = [&](size_t bytes) {
    char* p = ws + off;
    off += (bytes + 255) & ~(size_t)255;
    return p;
  };
  u16* hidden_bf = (u16*)alloc((size_t)BATCH * HDIM * 2);
  u16* wbuf      = (u16*)alloc((size_t)HDIM * HDIM * 2);
  u16* r1        = (u16*)alloc((size_t)BATCH * HDIM * 2);
  u16* r2        = (u16*)alloc((size_t)BATCH * HDIM * 2);
  int* idxc      = (int*)alloc((size_t)BATCH * 4);
  int* kinfo     = (int*)alloc(256);
  int* flag      = (int*)alloc(256);
  if (off > ws_size) return;

  u16*   simw  = (u16*)d_out;
  float* h1acc = (float*)d_out;
  (void)in_sizes; (void)n_in; (void)out_size;

  dim3 blk(256);
  dim3 blk5(512);

  detect_mask<<<1, 256, 0, stream>>>((const unsigned char*)mraw, BATCH, flag);
  compact_mask<<<1, 256, 0, stream>>>(mraw, flag, idxc, kinfo);

  cast_f32_bf16<<<(BATCH * HDIM / 4) / 256, 256, 0, stream>>>(hs, hidden_bf, BATCH * HDIM / 4);

  // proj = hidden @ Wsim^T  [B, H] -> r1
  cast_f32_bf16<<<(HDIM * HDIM / 4) / 256, 256, 0, stream>>>(Wsim, wbuf, HDIM * HDIM / 4);
  gemm256<EPI_BF16><<<dim3(HDIM / 256, BATCH / 256), blk5, 0, stream>>>(
      hidden_bf, HDIM, wbuf, HDIM, r1, HDIM, BATCH, HDIM, HDIM,
      nullptr, 0, 0, nullptr, nullptr, nullptr, nullptr);
  normalize_rows<<<BATCH, 256, 0, stream>>>(r1);

  gather_rows<<<BATCH, 256, 0, stream>>>(r1, r2, idxc, kinfo);

  // sim = normed @ normed_c^T  [B, kc_pad] (ld=BATCH) -> simw
  gemm256<EPI_SIM><<<dim3(BATCH / 256, BATCH / 256), blk5, 0, stream>>>(
      r1, HDIM, r2, HDIM, simw, BATCH, BATCH, BATCH, HDIM,
      kinfo, 1, 0, idxc, nullptr, nullptr, nullptr);
  softmax_rows_dyn<<<BATCH, 256, 0, stream>>>(simw, kinfo);

  gather_rows<<<BATCH, 256, 0, stream>>>(hidden_bf, r1, idxc, kinfo);

  // valuesT_c = Wval @ hidden_c^T  [H, kc_pad] (ld=BATCH) -> r2
  cast_f32_bf16<<<(HDIM * HDIM / 4) / 256, 256, 0, stream>>>(Wval, wbuf, HDIM * HDIM / 4);
  gemm256<EPI_BF16><<<dim3(BATCH / 256, HDIM / 256), blk5, 0, stream>>>(
      wbuf, HDIM, r1, HDIM, r2, BATCH, HDIM, BATCH, HDIM,
      kinfo, 1, 0, nullptr, nullptr, nullptr, nullptr);

  // cross = weights_c @ valuesT_c^T  [B, H], K = kc_pad -> r1
  gemm256<EPI_BF16><<<dim3(HDIM / 256, BATCH / 256), blk5, 0, stream>>>(
      simw, BATCH, r2, BATCH, r1, HDIM, BATCH, HDIM, BATCH,
      kinfo, 0, 1, nullptr, nullptr, nullptr, nullptr);

  // h1 pass 1: hidden @ Wg1[:, :H]^T -> fp32 acc (d_out)  [B, GH]
  cast_f32_bf16<<<(GHDIM * 2 * HDIM / 4) / 256, 256, 0, stream>>>(Wg1, wbuf, GHDIM * 2 * HDIM / 4);
  gemm_bt<EPI_F32><<<dim3(GHDIM / 128, BATCH / 128), blk, 0, stream>>>(
      hidden_bf, HDIM, wbuf, 2 * HDIM, h1acc, GHDIM, BATCH, GHDIM, HDIM,
      nullptr, 0, 0, nullptr, nullptr, nullptr, nullptr);
  // h1 pass 2: + cross @ Wg1[:, H:]^T, + b_g1, exact GELU -> r2
  gemm_bt<EPI_GELU><<<dim3(GHDIM / 128, BATCH / 128), blk, 0, stream>>>(
      r1, HDIM, wbuf + HDIM, 2 * HDIM, r2, GHDIM, BATCH, GHDIM, HDIM,
      nullptr, 0, 0, nullptr, h1acc, nullptr, bg1);

  // out = hidden + sigmoid(h1 @ Wg2^T + b_g2) * cross  [B, H] fp32 -> d_out
  cast_f32_bf16<<<(HDIM * GHDIM / 4) / 256, 256, 0, stream>>>(Wg2, wbuf, HDIM * GHDIM / 4);
  gemm256<EPI_FINAL><<<dim3(HDIM / 256, BATCH / 256), blk5, 0, stream>>>(
      r2, GHDIM, wbuf, GHDIM, out, HDIM, BATCH, HDIM, GHDIM,
      nullptr, 0, 0, nullptr, hs, r1, bg2);
}